// Round 1
// baseline (84932.660 us; speedup 1.0000x reference)
//
#include <hip/hip_runtime.h>
#include <cstdint>
#include <cstddef>

#define DEV __device__ __forceinline__

// Problem constants
constexpr int V  = 96103;
constexpr int D  = 1024;
constexpr int H  = 16;
constexpr int DH = 64;
constexpr int F  = 4096;
constexpr int NL = 2;     // layers
constexpr int S  = 512;
constexpr int T  = 80;
constexpr int B  = 4;
constexpr int NS = 5;
constexpr int BN = 20;    // B*NS
constexpr int KTOP = 100;
constexpr int EOS = 1;

// ---------------------------------------------------------------- utilities

DEV float gelu_f(float x) {
  // jax.nn.gelu approximate=True: x * (0.5*(1+tanh(sqrt(2/pi)*(x+0.044715*x^3))))
  float x3 = x * x * x;
  float inner = 0.7978845608028654f * (x + 0.044715f * x3);
  float tt = tanhf(inner);
  float cdf = 0.5f * (1.0f + tt);
  return x * cdf;
}

DEV void tf2x32(unsigned k0, unsigned k1, unsigned& x0, unsigned& x1) {
  // JAX threefry2x32 (20 rounds, key injection every 4)
  unsigned ks2 = k0 ^ k1 ^ 0x1BD11BDAu;
#define TFR(rr) { x0 += x1; x1 = (x1 << rr) | (x1 >> (32 - rr)); x1 ^= x0; }
  x0 += k0; x1 += k1;
  TFR(13) TFR(15) TFR(26) TFR(6)
  x0 += k1;  x1 += ks2 + 1u;
  TFR(17) TFR(29) TFR(16) TFR(24)
  x0 += ks2; x1 += k0 + 2u;
  TFR(13) TFR(15) TFR(26) TFR(6)
  x0 += k0;  x1 += k1 + 3u;
  TFR(17) TFR(29) TFR(16) TFR(24)
  x0 += k1;  x1 += ks2 + 4u;
  TFR(13) TFR(15) TFR(26) TFR(6)
  x0 += ks2; x1 += k0 + 5u;
#undef TFR
}

DEV unsigned long long sort_key(float v, unsigned idx) {
  // monotonic float->uint; key orders by (value asc, idx desc); we sort on ~key
  unsigned bb = __float_as_uint(v);
  bb = (bb & 0x80000000u) ? ~bb : (bb | 0x80000000u);
  return ((unsigned long long)bb << 32) | (unsigned long long)(0xFFFFFFFFu - idx);
}

// ---------------------------------------------------------------- embeddings

__global__ __launch_bounds__(256) void embed_enc(const int* __restrict__ ids,
                                                 const float* __restrict__ E,
                                                 const float* __restrict__ pos_e,
                                                 float* __restrict__ xe) {
  int row = blockIdx.x;               // b*S + s
  int id = ids[row];
  const float* er = E + (size_t)id * D;
  const float* pr = pos_e + (size_t)(row % S) * D;
  float* xr = xe + (size_t)row * D;
  for (int j = threadIdx.x; j < D; j += 256)
    xr[j] = er[j] * 32.0f + pr[j];
}

__global__ __launch_bounds__(256) void embed_dec(const float* __restrict__ E,
                                                 const float* __restrict__ pos_d,
                                                 const int* __restrict__ toks,
                                                 float* __restrict__ xd, int t) {
  int bn = blockIdx.x;
  int prev = (t == 0) ? 0 : toks[bn * T + (t - 1)];
  const float* er = E + (size_t)prev * D;
  const float* pr = pos_d + (size_t)t * D;
  float* xr = xd + (size_t)bn * D;
  for (int j = threadIdx.x; j < D; j += 256)
    xr[j] = er[j] * 32.0f + pr[j];
}

// ---------------------------------------------------------------- layernorm

__global__ __launch_bounds__(256) void ln_kernel(const float* __restrict__ x,
                                                 float* __restrict__ y) {
  __shared__ float red[256];
  __shared__ float sv[2];
  int tid = threadIdx.x;
  const float* xr = x + (size_t)blockIdx.x * D;
  float4 v = *(const float4*)(xr + tid * 4);
  red[tid] = v.x + v.y + v.z + v.w;
  __syncthreads();
  for (int k = 128; k > 0; k >>= 1) { if (tid < k) red[tid] += red[tid + k]; __syncthreads(); }
  if (tid == 0) sv[0] = red[0] * (1.0f / 1024.0f);
  __syncthreads();
  float m = sv[0];
  float dx = v.x - m, dy = v.y - m, dz = v.z - m, dw = v.w - m;
  red[tid] = dx * dx + dy * dy + dz * dz + dw * dw;
  __syncthreads();
  for (int k = 128; k > 0; k >>= 1) { if (tid < k) red[tid] += red[tid + k]; __syncthreads(); }
  if (tid == 0) sv[1] = 1.0f / sqrtf(red[0] * (1.0f / 1024.0f) + 1e-5f);
  __syncthreads();
  float r = sv[1];
  float* yr = y + (size_t)blockIdx.x * D;
  float4 o; o.x = dx * r; o.y = dy * r; o.z = dz * r; o.w = dw * r;
  *(float4*)(yr + tid * 4) = o;
}

// ---------------------------------------------------------------- big GEMM (encoder)
// C[M,N] = epi(A[M,K] @ W[K,N])  EPI: 0 none, 1 C=X+acc, 2 gelu

template<int EPI>
__global__ __launch_bounds__(256) void gemm64(const float* __restrict__ A,
                                              const float* __restrict__ W,
                                              const float* __restrict__ X,
                                              float* __restrict__ C,
                                              int Kd, int Nd) {
  __shared__ __align__(16) float As[16][64];
  __shared__ __align__(16) float Ws[16][64];
  int tid = threadIdx.x;
  int n0 = blockIdx.x * 64, m0 = blockIdx.y * 64;
  int tx = tid & 15, ty = tid >> 4;
  int ar = tid >> 2, ac = (tid & 3) * 4;
  int wr = tid >> 4, wc = (tid & 15) * 4;
  float acc[4][4] = {};
  for (int k0 = 0; k0 < Kd; k0 += 16) {
    float4 av = *(const float4*)(A + (size_t)(m0 + ar) * Kd + k0 + ac);
    float4 wv = *(const float4*)(W + (size_t)(k0 + wr) * Nd + n0 + wc);
    As[ac + 0][ar] = av.x; As[ac + 1][ar] = av.y;
    As[ac + 2][ar] = av.z; As[ac + 3][ar] = av.w;
    *(float4*)&Ws[wr][wc] = wv;
    __syncthreads();
#pragma unroll
    for (int k = 0; k < 16; ++k) {
      float4 a4 = *(const float4*)&As[k][ty * 4];
      float4 b4 = *(const float4*)&Ws[k][tx * 4];
      float avv[4] = {a4.x, a4.y, a4.z, a4.w};
      float bvv[4] = {b4.x, b4.y, b4.z, b4.w};
#pragma unroll
      for (int i = 0; i < 4; ++i)
#pragma unroll
        for (int j = 0; j < 4; ++j)
          acc[i][j] = fmaf(avv[i], bvv[j], acc[i][j]);
    }
    __syncthreads();
  }
#pragma unroll
  for (int i = 0; i < 4; ++i) {
    int m = m0 + ty * 4 + i;
#pragma unroll
    for (int j = 0; j < 4; ++j) {
      int n = n0 + tx * 4 + j;
      float r = acc[i][j];
      size_t off = (size_t)m * Nd + n;
      if (EPI == 1) r = X[off] + r;
      if (EPI == 2) r = gelu_f(r);
      C[off] = r;
    }
  }
}

// ---------------------------------------------------------------- encoder attention
// one block per (b,h,q)

__global__ __launch_bounds__(256) void enc_attn(const float* __restrict__ qkv,
                                                const int* __restrict__ mask,
                                                float* __restrict__ ab) {
  __shared__ __align__(16) float qv[64];
  __shared__ float sc[512];
  __shared__ float red[256];
  __shared__ float sv[2];
  int tid = threadIdx.x;
  int q = blockIdx.x % S;
  int h = (blockIdx.x / S) % H;
  int b = blockIdx.x / (S * H);
  const float* qrow = qkv + (size_t)(b * S + q) * (3 * D) + h * 64;
  if (tid < 64) qv[tid] = qrow[tid];
  __syncthreads();
  float lmax = -INFINITY;
  for (int k = tid; k < S; k += 256) {
    const float* kr = qkv + (size_t)(b * S + k) * (3 * D) + D + h * 64;
    float dot = 0.0f;
#pragma unroll
    for (int d4 = 0; d4 < 16; ++d4) {
      float4 kk = *(const float4*)(kr + d4 * 4);
      float4 qq = *(const float4*)(qv + d4 * 4);
      dot += qq.x * kk.x + qq.y * kk.y + qq.z * kk.z + qq.w * kk.w;
    }
    float bias = (1.0f - (float)mask[b * S + k]) * -1e9f;
    float val = dot * 0.125f + bias;
    sc[k] = val;
    lmax = fmaxf(lmax, val);
  }
  red[tid] = lmax; __syncthreads();
  for (int k = 128; k > 0; k >>= 1) { if (tid < k) red[tid] = fmaxf(red[tid], red[tid + k]); __syncthreads(); }
  if (tid == 0) sv[0] = red[0];
  __syncthreads();
  float mx = sv[0];
  float lsum = 0.0f;
  for (int k = tid; k < S; k += 256) { float e = expf(sc[k] - mx); sc[k] = e; lsum += e; }
  red[tid] = lsum; __syncthreads();
  for (int k = 128; k > 0; k >>= 1) { if (tid < k) red[tid] += red[tid + k]; __syncthreads(); }
  if (tid == 0) sv[1] = red[0];
  __syncthreads();
  float den = sv[1];
  for (int k = tid; k < S; k += 256) sc[k] = sc[k] / den;
  __syncthreads();
  int d = tid & 63, c = tid >> 6;
  const float* vb = qkv + (size_t)(b * S) * (3 * D) + 2 * D + h * 64 + d;
  float part = 0.0f;
  for (int k = c * 128; k < c * 128 + 128; ++k)
    part = fmaf(sc[k], vb[(size_t)k * (3 * D)], part);
  red[tid] = part; __syncthreads();
  if (tid < 64) {
    float o = red[tid] + red[tid + 64] + red[tid + 128] + red[tid + 192];
    ab[(size_t)(b * S + q) * D + h * 64 + tid] = o;
  }
}

// ---------------------------------------------------------------- decoder self-attn

__global__ __launch_bounds__(128) void dec_self_attn(const float* __restrict__ qkvd,
                                                     const float* __restrict__ cacheK,
                                                     const float* __restrict__ cacheV,
                                                     float* __restrict__ ad, int t, int l) {
  __shared__ __align__(16) float qv[64];
  __shared__ float sc[96];
  __shared__ float sv[2];
  int tid = threadIdx.x;
  int bn = blockIdx.x >> 4;
  int h = blockIdx.x & 15;
  int n = t + 1;
  if (tid < 64) qv[tid] = qkvd[(size_t)bn * (3 * D) + h * 64 + tid];
  __syncthreads();
  if (tid < n) {
    const float* kr = cacheK + (((size_t)l * BN + bn) * T + tid) * D + h * 64;
    float dot = 0.0f;
#pragma unroll
    for (int d4 = 0; d4 < 16; ++d4) {
      float4 kk = *(const float4*)(kr + d4 * 4);
      float4 qq = *(const float4*)(qv + d4 * 4);
      dot += qq.x * kk.x + qq.y * kk.y + qq.z * kk.z + qq.w * kk.w;
    }
    sc[tid] = dot * 0.125f;
  }
  __syncthreads();
  if (tid == 0) {
    float mx = -INFINITY;
    for (int k = 0; k < n; ++k) mx = fmaxf(mx, sc[k]);
    sv[0] = mx;
  }
  __syncthreads();
  if (tid < n) sc[tid] = expf(sc[tid] - sv[0]);
  __syncthreads();
  if (tid == 0) {
    float s = 0.0f;
    for (int k = 0; k < n; ++k) s += sc[k];
    sv[1] = s;
  }
  __syncthreads();
  if (tid < n) sc[tid] = sc[tid] / sv[1];
  __syncthreads();
  if (tid < 64) {
    const float* vb = cacheV + ((size_t)l * BN + bn) * T * D + h * 64 + tid;
    float o = 0.0f;
    for (int k = 0; k < n; ++k) o = fmaf(sc[k], vb[(size_t)k * D], o);
    ad[(size_t)bn * D + h * 64 + tid] = o;
  }
}

// ---------------------------------------------------------------- decoder cross-attn
// cKV layout: [L, B, S, 2D] (K at col h*64, V at col D + h*64)

__global__ __launch_bounds__(256) void dec_cross_attn(const float* __restrict__ q2,
                                                      const float* __restrict__ cKV,
                                                      const int* __restrict__ mask,
                                                      float* __restrict__ ad, int l) {
  __shared__ __align__(16) float qv[64];
  __shared__ float sc[512];
  __shared__ float red[256];
  __shared__ float sv[2];
  int tid = threadIdx.x;
  int bn = blockIdx.x >> 4;
  int h = blockIdx.x & 15;
  int b = bn / NS;
  const float* base = cKV + ((size_t)l * B + b) * S * (2 * D);
  if (tid < 64) qv[tid] = q2[(size_t)bn * D + h * 64 + tid];
  __syncthreads();
  float lmax = -INFINITY;
  for (int s = tid; s < S; s += 256) {
    const float* kr = base + (size_t)s * (2 * D) + h * 64;
    float dot = 0.0f;
#pragma unroll
    for (int d4 = 0; d4 < 16; ++d4) {
      float4 kk = *(const float4*)(kr + d4 * 4);
      float4 qq = *(const float4*)(qv + d4 * 4);
      dot += qq.x * kk.x + qq.y * kk.y + qq.z * kk.z + qq.w * kk.w;
    }
    float bias = (1.0f - (float)mask[b * S + s]) * -1e9f;
    float val = dot * 0.125f + bias;
    sc[s] = val;
    lmax = fmaxf(lmax, val);
  }
  red[tid] = lmax; __syncthreads();
  for (int k = 128; k > 0; k >>= 1) { if (tid < k) red[tid] = fmaxf(red[tid], red[tid + k]); __syncthreads(); }
  if (tid == 0) sv[0] = red[0];
  __syncthreads();
  float mx = sv[0];
  float lsum = 0.0f;
  for (int s = tid; s < S; s += 256) { float e = expf(sc[s] - mx); sc[s] = e; lsum += e; }
  red[tid] = lsum; __syncthreads();
  for (int k = 128; k > 0; k >>= 1) { if (tid < k) red[tid] += red[tid + k]; __syncthreads(); }
  if (tid == 0) sv[1] = red[0];
  __syncthreads();
  float den = sv[1];
  for (int s = tid; s < S; s += 256) sc[s] = sc[s] / den;
  __syncthreads();
  int d = tid & 63, c = tid >> 6;
  const float* vb = base + D + h * 64 + d;
  float part = 0.0f;
  for (int s = c * 128; s < c * 128 + 128; ++s)
    part = fmaf(sc[s], vb[(size_t)s * (2 * D)], part);
  red[tid] = part; __syncthreads();
  if (tid < 64) {
    float o = red[tid] + red[tid + 64] + red[tid + 128] + red[tid + 192];
    ad[(size_t)bn * D + h * 64 + tid] = o;
  }
}

// ---------------------------------------------------------------- KV cache store

__global__ __launch_bounds__(256) void store_kv(const float* __restrict__ qkvd,
                                                float* __restrict__ cacheK,
                                                float* __restrict__ cacheV, int t, int l) {
  int bn = blockIdx.x;
  size_t dst = (((size_t)l * BN + bn) * T + t) * D;
  for (int j = threadIdx.x; j < D; j += 256) {
    cacheK[dst + j] = qkvd[(size_t)bn * (3 * D) + D + j];
    cacheV[dst + j] = qkvd[(size_t)bn * (3 * D) + 2 * D + j];
  }
}

// ---------------------------------------------------------------- skinny GEMM (M=20) split-K
// partial[ky][20][N] = x[20, kchunk_ky] @ W[kchunk_ky, N]

__global__ __launch_bounds__(256) void skinny_gemm(const float* __restrict__ x,
                                                   const float* __restrict__ W,
                                                   float* __restrict__ partial,
                                                   int Kd, int Nd, int KS) {
  __shared__ __align__(16) float xs[10240];      // [kchunk][20], kchunk <= 512
  __shared__ float red2[4 * 20 * 64];
  int tid = threadIdx.x;
  int lane = tid & 63, w = tid >> 6;
  int kchunk = Kd / KS;
  int kb0 = blockIdx.y * kchunk;
  for (int i = tid; i < 20 * kchunk; i += 256) {
    int m = i / kchunk, kk = i - m * kchunk;
    xs[kk * 20 + m] = x[(size_t)m * Kd + kb0 + kk];
  }
  __syncthreads();
  int klen = kchunk >> 2;
  int kw0 = w * klen;
  float acc[20] = {};
  const float* Wp = W + (size_t)(kb0 + kw0) * Nd + blockIdx.x * 64 + lane;
  for (int kk = 0; kk < klen; ++kk) {
    float wv = Wp[(size_t)kk * Nd];
    const float* xk = xs + (kw0 + kk) * 20;
#pragma unroll
    for (int m4 = 0; m4 < 5; ++m4) {
      float4 xv = *(const float4*)(xk + m4 * 4);
      acc[m4 * 4 + 0] = fmaf(xv.x, wv, acc[m4 * 4 + 0]);
      acc[m4 * 4 + 1] = fmaf(xv.y, wv, acc[m4 * 4 + 1]);
      acc[m4 * 4 + 2] = fmaf(xv.z, wv, acc[m4 * 4 + 2]);
      acc[m4 * 4 + 3] = fmaf(xv.w, wv, acc[m4 * 4 + 3]);
    }
  }
#pragma unroll
  for (int m = 0; m < 20; ++m) red2[(w * 20 + m) * 64 + lane] = acc[m];
  __syncthreads();
  for (int i = tid; i < 20 * 64; i += 256) {
    int m = i >> 6, n = i & 63;
    float s2 = red2[(0 * 20 + m) * 64 + n] + red2[(1 * 20 + m) * 64 + n]
             + red2[(2 * 20 + m) * 64 + n] + red2[(3 * 20 + m) * 64 + n];
    partial[((size_t)blockIdx.y * 20 + m) * Nd + blockIdx.x * 64 + n] = s2;
  }
}

template<int EPI>
__global__ __launch_bounds__(256) void skinny_reduce(const float* __restrict__ partial,
                                                     const float* __restrict__ X,
                                                     float* __restrict__ C,
                                                     int Nd, int KS) {
  int i = blockIdx.x * 256 + threadIdx.x;
  if (i >= 20 * Nd) return;
  int m = i / Nd, n = i - m * Nd;
  float s = 0.0f;
  for (int ky = 0; ky < KS; ++ky) s += partial[((size_t)ky * 20 + m) * Nd + n];
  if (EPI == 1) s = X[i] + s;
  if (EPI == 2) s = gelu_f(s);
  C[i] = s;
}

// ---------------------------------------------------------------- logits = x @ E^T

__global__ __launch_bounds__(256) void logits_kernel(const float* __restrict__ x,
                                                     const float* __restrict__ E,
                                                     float* __restrict__ logits) {
  int n = blockIdx.x * 256 + threadIdx.x;
  if (n >= V) return;
  const float* er = E + (size_t)n * D;
  float acc[20] = {};
  for (int k4 = 0; k4 < D / 4; ++k4) {
    float4 e4 = *(const float4*)(er + k4 * 4);
#pragma unroll
    for (int m = 0; m < 20; ++m) {
      float4 xv = *(const float4*)(x + m * D + k4 * 4);
      acc[m] = fmaf(e4.x, xv.x, acc[m]);
      acc[m] = fmaf(e4.y, xv.y, acc[m]);
      acc[m] = fmaf(e4.z, xv.z, acc[m]);
      acc[m] = fmaf(e4.w, xv.w, acc[m]);
    }
  }
#pragma unroll
  for (int m = 0; m < 20; ++m) logits[(size_t)m * V + n] = acc[m];
}

// ---------------------------------------------------------------- top-k + gumbel sample
// one block per decode stream bn

__global__ __launch_bounds__(256) void topk_sample(const float* __restrict__ logits,
                                                   int* __restrict__ toks, int t) {
  __shared__ unsigned long long keys[4096];
  __shared__ float svals[128];
  __shared__ unsigned sidx[128];
  int tid = threadIdx.x;
  int bn = blockIdx.x;
  const float* row = logits + (size_t)bn * V;

  float tv[16]; unsigned ti[16];
#pragma unroll
  for (int j = 0; j < 16; ++j) { tv[j] = -INFINITY; ti[j] = 0xFFFFFFFFu; }

  for (int i = tid; i < V; i += 256) {
    float v = row[i];
    if (t < 6 && i == EOS) v = -1e9f;       // min_length EOS block
    if (v > tv[15]) {                        // ascending i -> strict > preserves tie rule
      tv[15] = v; ti[15] = (unsigned)i;
#pragma unroll
      for (int j = 15; j > 0; --j) {
        if (tv[j] > tv[j - 1]) {
          float a = tv[j]; tv[j] = tv[j - 1]; tv[j - 1] = a;
          unsigned bi = ti[j]; ti[j] = ti[j - 1]; ti[j - 1] = bi;
        }
      }
    }
  }
#pragma unroll
  for (int j = 0; j < 16; ++j) keys[tid * 16 + j] = ~sort_key(tv[j], ti[j]);
  __syncthreads();

  // bitonic ascending on inverted keys -> best first
  for (int ksz = 2; ksz <= 4096; ksz <<= 1) {
    for (int jj = ksz >> 1; jj > 0; jj >>= 1) {
      for (int i = tid; i < 4096; i += 256) {
        int ixj = i ^ jj;
        if (ixj > i) {
          unsigned long long a = keys[i], b2 = keys[ixj];
          bool up = ((i & ksz) == 0);
          if ((a > b2) == up) { keys[i] = b2; keys[ixj] = a; }
        }
      }
      __syncthreads();
    }
  }

  if (tid < KTOP) {
    unsigned long long kk = ~keys[tid];
    unsigned sb = (unsigned)(kk >> 32);
    unsigned idx = 0xFFFFFFFFu - (unsigned)(kk & 0xFFFFFFFFull);
    unsigned fb = (sb & 0x80000000u) ? (sb ^ 0x80000000u) : ~sb;
    float v = __uint_as_float(fb);
    // key_t = fold_in(key(1234), t)
    unsigned a0 = 0u, a1 = (unsigned)t;
    tf2x32(0u, 1234u, a0, a1);
    // partitionable threefry random_bits: bits[i] = o0 ^ o1 of threefry(key_t, (0, i))
    unsigned c0 = 0u, c1 = (unsigned)(bn * KTOP + tid);
    tf2x32(a0, a1, c0, c1);
    unsigned bits = c0 ^ c1;
    float f = __uint_as_float((bits >> 9) | 0x3f800000u) - 1.0f;
    float u = fmaxf(f, 1.17549435e-38f);
    float g = -logf(-logf(u));
    svals[tid] = v + g;
    sidx[tid] = idx;
  }
  __syncthreads();
  if (tid == 0) {
    int best = 0; float bv = svals[0];
    for (int j = 1; j < KTOP; ++j) { if (svals[j] > bv) { bv = svals[j]; best = j; } }
    toks[bn * T + t] = (int)sidx[best];
  }
}

// ---------------------------------------------------------------- host driver

extern "C" void kernel_launch(void* const* d_in, const int* in_sizes, int n_in,
                              void* d_out, int out_size, void* d_ws, size_t ws_size,
                              hipStream_t stream) {
  (void)in_sizes; (void)n_in; (void)out_size; (void)ws_size;

  const int*   ids      = (const int*)d_in[0];
  const int*   maskp    = (const int*)d_in[1];
  const float* E        = (const float*)d_in[2];
  const float* pos_e    = (const float*)d_in[3];
  const float* pos_d    = (const float*)d_in[4];
  const float* eai      = (const float*)d_in[5];   // enc_attn_in  [L,D,3D]
  const float* eao      = (const float*)d_in[6];   // enc_attn_out [L,D,D]
  const float* ef1      = (const float*)d_in[7];   // enc_ffn1     [L,D,F]
  const float* ef2      = (const float*)d_in[8];   // enc_ffn2     [L,F,D]
  const float* dsi      = (const float*)d_in[9];   // dec_sa_in    [L,D,3D]
  const float* dso      = (const float*)d_in[10];  // dec_sa_out   [L,D,D]
  const float* dcq      = (const float*)d_in[11];  // dec_ca_q     [L,D,D]
  const float* dckv     = (const float*)d_in[12];  // dec_ca_kv    [L,D,2D]
  const float* dco      = (const float*)d_in[13];  // dec_ca_out   [L,D,D]
  const float* df1      = (const float*)d_in[14];  // dec_ffn1     [L,D,F]
  const float* df2      = (const float*)d_in[15];  // dec_ffn2     [L,F,D]

  float* ws = (float*)d_ws;
  size_t o = 0;
  auto alloc = [&](size_t n) { size_t r = o; o += (n + 63) & ~(size_t)63; return r; };
  float* cKV    = ws + alloc((size_t)NL * B * S * 2 * D);   //  33.5 MB
  float* cacheK = ws + alloc((size_t)NL * BN * T * D);      //  13.1 MB
  float* cacheV = ws + alloc((size_t)NL * BN * T * D);      //  13.1 MB
  float* xe     = ws + alloc((size_t)B * S * D);            //   8.4 MB
  float* he     = ws + alloc((size_t)B * S * D);            //   8.4 MB
  float* qkvb   = ws + alloc((size_t)B * S * 3 * D);        //  25.2 MB
  float* ab     = ws + alloc((size_t)B * S * D);            //   8.4 MB
  float* ffb    = ws + alloc((size_t)B * S * F);            //  33.5 MB
  // decoder scratch aliases the (then-idle) qkvb region (needs ~2.8M floats < 6.29M)
  float* xd     = qkvb;
  float* hd     = xd + BN * D;
  float* q2     = hd + BN * D;
  float* ad     = q2 + BN * D;
  float* qkvd   = ad + BN * D;
  float* ffd    = qkvd + BN * 3 * D;
  float* part   = ffd + BN * F;
  float* logitsb= part + 8 * BN * F;                        // max KS(8) * 20 * N(4096)
  int* toks = (int*)d_out;

  // ---------------- encoder ----------------
  embed_enc<<<B * S, 256, 0, stream>>>(ids, E, pos_e, xe);
  for (int l = 0; l < NL; ++l) {
    ln_kernel<<<B * S, 256, 0, stream>>>(xe, he);
    gemm64<0><<<dim3(3 * D / 64, B * S / 64), 256, 0, stream>>>(
        he, eai + (size_t)l * D * 3 * D, nullptr, qkvb, D, 3 * D);
    enc_attn<<<B * H * S, 256, 0, stream>>>(qkvb, maskp, ab);
    gemm64<1><<<dim3(D / 64, B * S / 64), 256, 0, stream>>>(
        ab, eao + (size_t)l * D * D, xe, xe, D, D);
    ln_kernel<<<B * S, 256, 0, stream>>>(xe, he);
    gemm64<2><<<dim3(F / 64, B * S / 64), 256, 0, stream>>>(
        he, ef1 + (size_t)l * D * F, nullptr, ffb, D, F);
    gemm64<1><<<dim3(D / 64, B * S / 64), 256, 0, stream>>>(
        ffb, ef2 + (size_t)l * F * D, xe, xe, F, D);
  }
  ln_kernel<<<B * S, 256, 0, stream>>>(xe, he);   // he = enc
  for (int l = 0; l < NL; ++l) {
    gemm64<0><<<dim3(2 * D / 64, B * S / 64), 256, 0, stream>>>(
        he, dckv + (size_t)l * D * 2 * D, nullptr,
        cKV + (size_t)l * B * S * 2 * D, D, 2 * D);
  }

  // ---------------- decoder: 80 sequential sampling steps ----------------
  for (int t = 0; t < T; ++t) {
    embed_dec<<<BN, 256, 0, stream>>>(E, pos_d, toks, xd, t);
    for (int l = 0; l < NL; ++l) {
      // self-attention
      ln_kernel<<<BN, 256, 0, stream>>>(xd, hd);
      skinny_gemm<<<dim3(3 * D / 64, 4), 256, 0, stream>>>(
          hd, dsi + (size_t)l * D * 3 * D, part, D, 3 * D, 4);
      skinny_reduce<0><<<(BN * 3 * D + 255) / 256, 256, 0, stream>>>(part, nullptr, qkvd, 3 * D, 4);
      store_kv<<<BN, 256, 0, stream>>>(qkvd, cacheK, cacheV, t, l);
      dec_self_attn<<<BN * H, 128, 0, stream>>>(qkvd, cacheK, cacheV, ad, t, l);
      skinny_gemm<<<dim3(D / 64, 4), 256, 0, stream>>>(
          ad, dso + (size_t)l * D * D, part, D, D, 4);
      skinny_reduce<1><<<(BN * D + 255) / 256, 256, 0, stream>>>(part, xd, xd, D, 4);
      // cross-attention
      ln_kernel<<<BN, 256, 0, stream>>>(xd, hd);
      skinny_gemm<<<dim3(D / 64, 4), 256, 0, stream>>>(
          hd, dcq + (size_t)l * D * D, part, D, D, 4);
      skinny_reduce<0><<<(BN * D + 255) / 256, 256, 0, stream>>>(part, nullptr, q2, D, 4);
      dec_cross_attn<<<BN * H, 256, 0, stream>>>(q2, cKV, maskp, ad, l);
      skinny_gemm<<<dim3(D / 64, 4), 256, 0, stream>>>(
          ad, dco + (size_t)l * D * D, part, D, D, 4);
      skinny_reduce<1><<<(BN * D + 255) / 256, 256, 0, stream>>>(part, xd, xd, D, 4);
      // ffn
      ln_kernel<<<BN, 256, 0, stream>>>(xd, hd);
      skinny_gemm<<<dim3(F / 64, 4), 256, 0, stream>>>(
          hd, df1 + (size_t)l * D * F, part, D, F, 4);
      skinny_reduce<2><<<(BN * F + 255) / 256, 256, 0, stream>>>(part, nullptr, ffd, F, 4);
      skinny_gemm<<<dim3(D / 64, 8), 256, 0, stream>>>(
          ffd, df2 + (size_t)l * F * D, part, F, D, 8);
      skinny_reduce<1><<<(BN * D + 255) / 256, 256, 0, stream>>>(part, xd, xd, D, 8);
    }
    ln_kernel<<<BN, 256, 0, stream>>>(xd, hd);
    logits_kernel<<<(V + 255) / 256, 256, 0, stream>>>(hd, E, logitsb);
    topk_sample<<<BN, 256, 0, stream>>>(logitsb, toks, t);
  }
}

// Round 2
// 78392.407 us; speedup vs baseline: 1.0834x; 1.0834x over previous
//
#include <hip/hip_runtime.h>
#include <cstdint>
#include <cstddef>

#define DEV __device__ __forceinline__

// Problem constants
constexpr int V  = 96103;
constexpr int D  = 1024;
constexpr int H  = 16;
constexpr int DH = 64;
constexpr int F  = 4096;
constexpr int NL = 2;     // layers
constexpr int S  = 512;
constexpr int T  = 80;
constexpr int B  = 4;
constexpr int NS = 5;
constexpr int BN = 20;    // B*NS
constexpr int KTOP = 100;
constexpr int EOS = 1;

// ---------------------------------------------------------------- utilities

DEV float gelu_f(float x) {
  float x3 = x * x * x;
  float inner = 0.7978845608028654f * (x + 0.044715f * x3);
  float tt = tanhf(inner);
  return x * (0.5f * (1.0f + tt));
}

DEV void tf2x32(unsigned k0, unsigned k1, unsigned& x0, unsigned& x1) {
  unsigned ks2 = k0 ^ k1 ^ 0x1BD11BDAu;
#define TFR(rr) { x0 += x1; x1 = (x1 << rr) | (x1 >> (32 - rr)); x1 ^= x0; }
  x0 += k0; x1 += k1;
  TFR(13) TFR(15) TFR(26) TFR(6)
  x0 += k1;  x1 += ks2 + 1u;
  TFR(17) TFR(29) TFR(16) TFR(24)
  x0 += ks2; x1 += k0 + 2u;
  TFR(13) TFR(15) TFR(26) TFR(6)
  x0 += k0;  x1 += k1 + 3u;
  TFR(17) TFR(29) TFR(16) TFR(24)
  x0 += k1;  x1 += ks2 + 4u;
  TFR(13) TFR(15) TFR(26) TFR(6)
  x0 += ks2; x1 += k0 + 5u;
#undef TFR
}

DEV unsigned long long sort_key(float v, unsigned idx) {
  unsigned bb = __float_as_uint(v);
  bb = (bb & 0x80000000u) ? ~bb : (bb | 0x80000000u);
  return ((unsigned long long)bb << 32) | (unsigned long long)(0xFFFFFFFFu - idx);
}

// wave-parallel LN of BN x 1024 rows into LDS xs[20][1024]
// NWAVE waves, each wave handles rows m = w, w+NWAVE, ...
template<int NWAVE>
DEV void ln_to_lds(const float* __restrict__ x, float* xs, int tid) {
  int w = tid >> 6, lane = tid & 63;
  for (int m = w; m < BN; m += NWAVE) {
    float4 v[4];
    float sum = 0.0f;
#pragma unroll
    for (int j = 0; j < 4; ++j) {
      v[j] = *(const float4*)(x + m * D + j * 256 + lane * 4);
      sum += v[j].x + v[j].y + v[j].z + v[j].w;
    }
#pragma unroll
    for (int o = 32; o > 0; o >>= 1) sum += __shfl_xor(sum, o);
    float mean = sum * (1.0f / 1024.0f);
    float vs = 0.0f;
#pragma unroll
    for (int j = 0; j < 4; ++j) {
      float a = v[j].x - mean, b = v[j].y - mean, c = v[j].z - mean, d = v[j].w - mean;
      vs += a * a + b * b + c * c + d * d;
    }
#pragma unroll
    for (int o = 32; o > 0; o >>= 1) vs += __shfl_xor(vs, o);
    float rsig = 1.0f / sqrtf(vs * (1.0f / 1024.0f) + 1e-5f);
#pragma unroll
    for (int j = 0; j < 4; ++j) {
      float4 ov;
      ov.x = (v[j].x - mean) * rsig; ov.y = (v[j].y - mean) * rsig;
      ov.z = (v[j].z - mean) * rsig; ov.w = (v[j].w - mean) * rsig;
      *(float4*)(xs + m * D + j * 256 + lane * 4) = ov;
    }
  }
}

// ---------------------------------------------------------------- embeddings

__global__ __launch_bounds__(256) void embed_enc(const int* __restrict__ ids,
                                                 const float* __restrict__ E,
                                                 const float* __restrict__ pos_e,
                                                 float* __restrict__ xe) {
  int row = blockIdx.x;
  int id = ids[row];
  const float* er = E + (size_t)id * D;
  const float* pr = pos_e + (size_t)(row % S) * D;
  float* xr = xe + (size_t)row * D;
  for (int j = threadIdx.x; j < D; j += 256)
    xr[j] = er[j] * 32.0f + pr[j];
}

__global__ __launch_bounds__(256) void embed_dec(const float* __restrict__ E,
                                                 const float* __restrict__ pos_d,
                                                 const int* __restrict__ toks,
                                                 float* __restrict__ xd, int t) {
  int bn = blockIdx.x;
  int prev = (t == 0) ? 0 : toks[bn * T + (t - 1)];
  const float* er = E + (size_t)prev * D;
  const float* pr = pos_d + (size_t)t * D;
  float* xr = xd + (size_t)bn * D;
  for (int j = threadIdx.x; j < D; j += 256)
    xr[j] = er[j] * 32.0f + pr[j];
}

// ---------------------------------------------------------------- layernorm (encoder)

__global__ __launch_bounds__(256) void ln_kernel(const float* __restrict__ x,
                                                 float* __restrict__ y) {
  __shared__ float red[256];
  __shared__ float sv[2];
  int tid = threadIdx.x;
  const float* xr = x + (size_t)blockIdx.x * D;
  float4 v = *(const float4*)(xr + tid * 4);
  red[tid] = v.x + v.y + v.z + v.w;
  __syncthreads();
  for (int k = 128; k > 0; k >>= 1) { if (tid < k) red[tid] += red[tid + k]; __syncthreads(); }
  if (tid == 0) sv[0] = red[0] * (1.0f / 1024.0f);
  __syncthreads();
  float m = sv[0];
  float dx = v.x - m, dy = v.y - m, dz = v.z - m, dw = v.w - m;
  red[tid] = dx * dx + dy * dy + dz * dz + dw * dw;
  __syncthreads();
  for (int k = 128; k > 0; k >>= 1) { if (tid < k) red[tid] += red[tid + k]; __syncthreads(); }
  if (tid == 0) sv[1] = 1.0f / sqrtf(red[0] * (1.0f / 1024.0f) + 1e-5f);
  __syncthreads();
  float r = sv[1];
  float* yr = y + (size_t)blockIdx.x * D;
  float4 o; o.x = dx * r; o.y = dy * r; o.z = dz * r; o.w = dw * r;
  *(float4*)(yr + tid * 4) = o;
}

// ---------------------------------------------------------------- encoder GEMM 128x128
// C[M,N] = epi(A[M,K] @ W[K,N]); EPI: 0 none, 1 C=X+acc, 2 gelu

template<int EPI>
__global__ __launch_bounds__(256) void gemm128(const float* __restrict__ A,
                                               const float* __restrict__ W,
                                               const float* X, float* C,
                                               int Kd, int Nd) {
  __shared__ __align__(16) float As[8][128];
  __shared__ __align__(16) float Bs[8][128];
  int tid = threadIdx.x;
  int n0 = blockIdx.x * 128, m0 = blockIdx.y * 128;
  int tx = tid & 15, ty = tid >> 4;
  int ar = tid >> 1, ac = (tid & 1) * 4;
  int br = tid >> 5, bc = (tid & 31) * 4;
  float acc[8][8] = {};
  for (int k0 = 0; k0 < Kd; k0 += 8) {
    float4 av = *(const float4*)(A + (size_t)(m0 + ar) * Kd + k0 + ac);
    float4 wv = *(const float4*)(W + (size_t)(k0 + br) * Nd + n0 + bc);
    __syncthreads();
    As[ac + 0][ar] = av.x; As[ac + 1][ar] = av.y;
    As[ac + 2][ar] = av.z; As[ac + 3][ar] = av.w;
    *(float4*)&Bs[br][bc] = wv;
    __syncthreads();
#pragma unroll
    for (int k = 0; k < 8; ++k) {
      float a8[8], b8[8];
      *(float4*)&a8[0] = *(const float4*)&As[k][ty * 8];
      *(float4*)&a8[4] = *(const float4*)&As[k][ty * 8 + 4];
      *(float4*)&b8[0] = *(const float4*)&Bs[k][tx * 8];
      *(float4*)&b8[4] = *(const float4*)&Bs[k][tx * 8 + 4];
#pragma unroll
      for (int i = 0; i < 8; ++i)
#pragma unroll
        for (int j = 0; j < 8; ++j)
          acc[i][j] = fmaf(a8[i], b8[j], acc[i][j]);
    }
  }
#pragma unroll
  for (int i = 0; i < 8; ++i) {
    int m = m0 + ty * 8 + i;
#pragma unroll
    for (int j = 0; j < 8; ++j) {
      int n = n0 + tx * 8 + j;
      float r = acc[i][j];
      size_t off = (size_t)m * Nd + n;
      if (EPI == 1) r = X[off] + r;
      if (EPI == 2) r = gelu_f(r);
      C[off] = r;
    }
  }
}

// ---------------------------------------------------------------- encoder attention

__global__ __launch_bounds__(256) void enc_attn(const float* __restrict__ qkv,
                                                const int* __restrict__ mask,
                                                float* __restrict__ ab) {
  __shared__ __align__(16) float qv[64];
  __shared__ float sc[512];
  __shared__ float red[256];
  __shared__ float sv[2];
  int tid = threadIdx.x;
  int q = blockIdx.x % S;
  int h = (blockIdx.x / S) % H;
  int b = blockIdx.x / (S * H);
  const float* qrow = qkv + (size_t)(b * S + q) * (3 * D) + h * 64;
  if (tid < 64) qv[tid] = qrow[tid];
  __syncthreads();
  float lmax = -INFINITY;
  for (int k = tid; k < S; k += 256) {
    const float* kr = qkv + (size_t)(b * S + k) * (3 * D) + D + h * 64;
    float dot = 0.0f;
#pragma unroll
    for (int d4 = 0; d4 < 16; ++d4) {
      float4 kk = *(const float4*)(kr + d4 * 4);
      float4 qq = *(const float4*)(qv + d4 * 4);
      dot += qq.x * kk.x + qq.y * kk.y + qq.z * kk.z + qq.w * kk.w;
    }
    float bias = (1.0f - (float)mask[b * S + k]) * -1e9f;
    float val = dot * 0.125f + bias;
    sc[k] = val;
    lmax = fmaxf(lmax, val);
  }
  red[tid] = lmax; __syncthreads();
  for (int k = 128; k > 0; k >>= 1) { if (tid < k) red[tid] = fmaxf(red[tid], red[tid + k]); __syncthreads(); }
  if (tid == 0) sv[0] = red[0];
  __syncthreads();
  float mx = sv[0];
  float lsum = 0.0f;
  for (int k = tid; k < S; k += 256) { float e = expf(sc[k] - mx); sc[k] = e; lsum += e; }
  red[tid] = lsum; __syncthreads();
  for (int k = 128; k > 0; k >>= 1) { if (tid < k) red[tid] += red[tid + k]; __syncthreads(); }
  if (tid == 0) sv[1] = red[0];
  __syncthreads();
  float den = sv[1];
  for (int k = tid; k < S; k += 256) sc[k] = sc[k] / den;
  __syncthreads();
  int d = tid & 63, c = tid >> 6;
  const float* vb = qkv + (size_t)(b * S) * (3 * D) + 2 * D + h * 64 + d;
  float part = 0.0f;
  for (int k = c * 128; k < c * 128 + 128; ++k)
    part = fmaf(sc[k], vb[(size_t)k * (3 * D)], part);
  red[tid] = part; __syncthreads();
  if (tid < 64) {
    float o = red[tid] + red[tid + 64] + red[tid + 128] + red[tid + 192];
    ab[(size_t)(b * S + q) * D + h * 64 + tid] = o;
  }
}

// ---------------------------------------------------------------- fused decode GEMM
// out[20,Nd] = epi( LN?(x)[20,Kd] @ W[Kd,Nd] )
// 512 threads: c=tid&15 (col in 16-col tile), ks=tid>>4 (32-way K split)
// EPI: 0 none, 1 residual add, 2 gelu.  KV: qkv epilogue routing to caches.

template<int EPI, bool LNIN, bool KV>
__global__ __launch_bounds__(512) void dec_gemm(const float* __restrict__ x,
                                                const float* __restrict__ W,
                                                const float* Xres, float* Cout,
                                                float* __restrict__ cacheK,
                                                float* __restrict__ cacheV,
                                                int Kd, int Nd, int t, int l) {
  __shared__ float red[16 * 20 * 33];
  __shared__ float xs[LNIN ? 20 * 1024 : 16];
  int tid = threadIdx.x;
  if constexpr (LNIN) {
    ln_to_lds<8>(x, xs, tid);
    __syncthreads();
  }
  int c = tid & 15, ks = tid >> 4;
  int klen = Kd >> 5;
  const float* Wp = W + (size_t)(ks * klen) * Nd + blockIdx.x * 16 + c;
  float acc[20] = {};
  for (int kk = 0; kk < klen; kk += 8) {
    float wv[8];
#pragma unroll
    for (int u = 0; u < 8; ++u) wv[u] = Wp[(size_t)u * Nd];
    Wp += (size_t)8 * Nd;
    int kb = ks * klen + kk;
#pragma unroll
    for (int m = 0; m < 20; ++m) {
      float4 x0, x1;
      if constexpr (LNIN) {
        x0 = *(const float4*)(xs + m * 1024 + kb);
        x1 = *(const float4*)(xs + m * 1024 + kb + 4);
      } else {
        x0 = *(const float4*)(x + (size_t)m * Kd + kb);
        x1 = *(const float4*)(x + (size_t)m * Kd + kb + 4);
      }
      float a = acc[m];
      a = fmaf(x0.x, wv[0], a); a = fmaf(x0.y, wv[1], a);
      a = fmaf(x0.z, wv[2], a); a = fmaf(x0.w, wv[3], a);
      a = fmaf(x1.x, wv[4], a); a = fmaf(x1.y, wv[5], a);
      a = fmaf(x1.z, wv[6], a); a = fmaf(x1.w, wv[7], a);
      acc[m] = a;
    }
  }
#pragma unroll
  for (int m = 0; m < 20; ++m) red[(c * 20 + m) * 33 + ks] = acc[m];
  __syncthreads();
  if (tid < 320) {
    int cc = tid & 15, m = tid >> 4;
    const float* rp = red + (cc * 20 + m) * 33;
    float s = 0.0f;
#pragma unroll
    for (int k2 = 0; k2 < 32; ++k2) s += rp[k2];
    int ng = blockIdx.x * 16 + cc;
    if constexpr (KV) {
      if (ng < D) {
        Cout[(size_t)m * Nd + ng] = s;                    // q -> qkvd
      } else if (ng < 2 * D) {
        cacheK[(((size_t)l * BN + m) * T + t) * D + (ng - D)] = s;
      } else {
        cacheV[(((size_t)l * BN + m) * T + t) * D + (ng - 2 * D)] = s;
      }
    } else {
      size_t off = (size_t)m * Nd + ng;
      if (EPI == 1) s = Xres[off] + s;
      if (EPI == 2) s = gelu_f(s);
      Cout[off] = s;
    }
  }
}

// ---------------------------------------------------------------- decoder self-attn

__global__ __launch_bounds__(128) void dec_self_attn(const float* __restrict__ qkvd,
                                                     const float* __restrict__ cacheK,
                                                     const float* __restrict__ cacheV,
                                                     float* __restrict__ ad, int t, int l) {
  __shared__ __align__(16) float qv[64];
  __shared__ float sc[96];
  __shared__ float sv[2];
  int tid = threadIdx.x;
  int bn = blockIdx.x >> 4;
  int h = blockIdx.x & 15;
  int n = t + 1;
  if (tid < 64) qv[tid] = qkvd[(size_t)bn * (3 * D) + h * 64 + tid];
  __syncthreads();
  if (tid < n) {
    const float* kr = cacheK + (((size_t)l * BN + bn) * T + tid) * D + h * 64;
    float dot = 0.0f;
#pragma unroll
    for (int d4 = 0; d4 < 16; ++d4) {
      float4 kk = *(const float4*)(kr + d4 * 4);
      float4 qq = *(const float4*)(qv + d4 * 4);
      dot += qq.x * kk.x + qq.y * kk.y + qq.z * kk.z + qq.w * kk.w;
    }
    sc[tid] = dot * 0.125f;
  }
  __syncthreads();
  if (tid == 0) {
    float mx = -INFINITY;
    for (int k = 0; k < n; ++k) mx = fmaxf(mx, sc[k]);
    sv[0] = mx;
  }
  __syncthreads();
  if (tid < n) sc[tid] = expf(sc[tid] - sv[0]);
  __syncthreads();
  if (tid == 0) {
    float s = 0.0f;
    for (int k = 0; k < n; ++k) s += sc[k];
    sv[1] = s;
  }
  __syncthreads();
  if (tid < n) sc[tid] = sc[tid] / sv[1];
  __syncthreads();
  if (tid < 64) {
    const float* vb = cacheV + ((size_t)l * BN + bn) * T * D + h * 64 + tid;
    float o = 0.0f;
    for (int k = 0; k < n; ++k) o = fmaf(sc[k], vb[(size_t)k * D], o);
    ad[(size_t)bn * D + h * 64 + tid] = o;
  }
}

// ---------------------------------------------------------------- decoder cross-attn

__global__ __launch_bounds__(256) void dec_cross_attn(const float* __restrict__ q2,
                                                      const float* __restrict__ cKV,
                                                      const int* __restrict__ mask,
                                                      float* __restrict__ ad, int l) {
  __shared__ __align__(16) float qv[64];
  __shared__ float sc[512];
  __shared__ float red[256];
  __shared__ float sv[2];
  int tid = threadIdx.x;
  int bn = blockIdx.x >> 4;
  int h = blockIdx.x & 15;
  int b = bn / NS;
  const float* base = cKV + ((size_t)l * B + b) * S * (2 * D);
  if (tid < 64) qv[tid] = q2[(size_t)bn * D + h * 64 + tid];
  __syncthreads();
  float lmax = -INFINITY;
  for (int s = tid; s < S; s += 256) {
    const float* kr = base + (size_t)s * (2 * D) + h * 64;
    float dot = 0.0f;
#pragma unroll
    for (int d4 = 0; d4 < 16; ++d4) {
      float4 kk = *(const float4*)(kr + d4 * 4);
      float4 qq = *(const float4*)(qv + d4 * 4);
      dot += qq.x * kk.x + qq.y * kk.y + qq.z * kk.z + qq.w * kk.w;
    }
    float bias = (1.0f - (float)mask[b * S + s]) * -1e9f;
    float val = dot * 0.125f + bias;
    sc[s] = val;
    lmax = fmaxf(lmax, val);
  }
  red[tid] = lmax; __syncthreads();
  for (int k = 128; k > 0; k >>= 1) { if (tid < k) red[tid] = fmaxf(red[tid], red[tid + k]); __syncthreads(); }
  if (tid == 0) sv[0] = red[0];
  __syncthreads();
  float mx = sv[0];
  float lsum = 0.0f;
  for (int s = tid; s < S; s += 256) { float e = expf(sc[s] - mx); sc[s] = e; lsum += e; }
  red[tid] = lsum; __syncthreads();
  for (int k = 128; k > 0; k >>= 1) { if (tid < k) red[tid] += red[tid + k]; __syncthreads(); }
  if (tid == 0) sv[1] = red[0];
  __syncthreads();
  float den = sv[1];
  for (int s = tid; s < S; s += 256) sc[s] = sc[s] / den;
  __syncthreads();
  int d = tid & 63, c = tid >> 6;
  const float* vb = base + D + h * 64 + d;
  float part = 0.0f;
  for (int s = c * 128; s < c * 128 + 128; ++s)
    part = fmaf(sc[s], vb[(size_t)s * (2 * D)], part);
  red[tid] = part; __syncthreads();
  if (tid < 64) {
    float o = red[tid] + red[tid + 64] + red[tid + 128] + red[tid + 192];
    ad[(size_t)bn * D + h * 64 + tid] = o;
  }
}

// ---------------------------------------------------------------- logits = LN(x) @ E^T

__global__ __launch_bounds__(256) void logits_ln(const float* __restrict__ xd,
                                                 const float* __restrict__ E,
                                                 float* __restrict__ logits) {
  __shared__ float xs[20 * 1024];
  int tid = threadIdx.x;
  ln_to_lds<4>(xd, xs, tid);
  __syncthreads();
  int n = blockIdx.x * 256 + tid;
  if (n >= V) return;
  const float* er = E + (size_t)n * D;
  float acc[20] = {};
  for (int k4 = 0; k4 < D / 4; ++k4) {
    float4 e4 = *(const float4*)(er + k4 * 4);
#pragma unroll
    for (int m = 0; m < 20; ++m) {
      float4 xv = *(const float4*)(xs + m * 1024 + k4 * 4);
      float a = acc[m];
      a = fmaf(e4.x, xv.x, a); a = fmaf(e4.y, xv.y, a);
      a = fmaf(e4.z, xv.z, a); a = fmaf(e4.w, xv.w, a);
      acc[m] = a;
    }
  }
#pragma unroll
  for (int m = 0; m < 20; ++m) logits[(size_t)m * V + n] = acc[m];
}

// ---------------------------------------------------------------- top-k + gumbel sample

__global__ __launch_bounds__(256) void topk_sample(const float* __restrict__ logits,
                                                   int* __restrict__ toks, int t) {
  __shared__ unsigned long long keys[4096];
  __shared__ float svals[128];
  __shared__ unsigned sidx[128];
  int tid = threadIdx.x;
  int bn = blockIdx.x;
  const float* row = logits + (size_t)bn * V;

  float tv[16]; unsigned ti[16];
#pragma unroll
  for (int j = 0; j < 16; ++j) { tv[j] = -INFINITY; ti[j] = 0xFFFFFFFFu; }

  for (int i = tid; i < V; i += 256) {
    float v = row[i];
    if (t < 6 && i == EOS) v = -1e9f;
    if (v > tv[15]) {
      tv[15] = v; ti[15] = (unsigned)i;
#pragma unroll
      for (int j = 15; j > 0; --j) {
        if (tv[j] > tv[j - 1]) {
          float a = tv[j]; tv[j] = tv[j - 1]; tv[j - 1] = a;
          unsigned bi = ti[j]; ti[j] = ti[j - 1]; ti[j - 1] = bi;
        }
      }
    }
  }
#pragma unroll
  for (int j = 0; j < 16; ++j) keys[tid * 16 + j] = ~sort_key(tv[j], ti[j]);
  __syncthreads();

  for (int ksz = 2; ksz <= 4096; ksz <<= 1) {
    for (int jj = ksz >> 1; jj > 0; jj >>= 1) {
      for (int i = tid; i < 4096; i += 256) {
        int ixj = i ^ jj;
        if (ixj > i) {
          unsigned long long a = keys[i], b2 = keys[ixj];
          bool up = ((i & ksz) == 0);
          if ((a > b2) == up) { keys[i] = b2; keys[ixj] = a; }
        }
      }
      __syncthreads();
    }
  }

  if (tid < KTOP) {
    unsigned long long kk = ~keys[tid];
    unsigned sb = (unsigned)(kk >> 32);
    unsigned idx = 0xFFFFFFFFu - (unsigned)(kk & 0xFFFFFFFFull);
    unsigned fb = (sb & 0x80000000u) ? (sb ^ 0x80000000u) : ~sb;
    float v = __uint_as_float(fb);
    unsigned a0 = 0u, a1 = (unsigned)t;
    tf2x32(0u, 1234u, a0, a1);
    unsigned c0 = 0u, c1 = (unsigned)(bn * KTOP + tid);
    tf2x32(a0, a1, c0, c1);
    unsigned bits = c0 ^ c1;
    float f = __uint_as_float((bits >> 9) | 0x3f800000u) - 1.0f;
    float u = fmaxf(f, 1.17549435e-38f);
    float g = -logf(-logf(u));
    svals[tid] = v + g;
    sidx[tid] = idx;
  }
  __syncthreads();
  if (tid == 0) {
    int best = 0; float bv = svals[0];
    for (int j = 1; j < KTOP; ++j) { if (svals[j] > bv) { bv = svals[j]; best = j; } }
    toks[bn * T + t] = (int)sidx[best];
  }
}

// ---------------------------------------------------------------- host driver

extern "C" void kernel_launch(void* const* d_in, const int* in_sizes, int n_in,
                              void* d_out, int out_size, void* d_ws, size_t ws_size,
                              hipStream_t stream) {
  (void)in_sizes; (void)n_in; (void)out_size; (void)ws_size;

  const int*   ids   = (const int*)d_in[0];
  const int*   maskp = (const int*)d_in[1];
  const float* E     = (const float*)d_in[2];
  const float* pos_e = (const float*)d_in[3];
  const float* pos_d = (const float*)d_in[4];
  const float* eai   = (const float*)d_in[5];
  const float* eao   = (const float*)d_in[6];
  const float* ef1   = (const float*)d_in[7];
  const float* ef2   = (const float*)d_in[8];
  const float* dsi   = (const float*)d_in[9];
  const float* dso   = (const float*)d_in[10];
  const float* dcq   = (const float*)d_in[11];
  const float* dckv  = (const float*)d_in[12];
  const float* dco   = (const float*)d_in[13];
  const float* df1   = (const float*)d_in[14];
  const float* df2   = (const float*)d_in[15];

  float* ws = (float*)d_ws;
  size_t o = 0;
  auto alloc = [&](size_t n) { size_t r = o; o += (n + 63) & ~(size_t)63; return r; };
  float* cKV    = ws + alloc((size_t)NL * B * S * 2 * D);
  float* cacheK = ws + alloc((size_t)NL * BN * T * D);
  float* cacheV = ws + alloc((size_t)NL * BN * T * D);
  float* xe     = ws + alloc((size_t)B * S * D);
  float* he     = ws + alloc((size_t)B * S * D);
  float* qkvb   = ws + alloc((size_t)B * S * 3 * D);
  float* ab     = ws + alloc((size_t)B * S * D);
  float* ffb    = ws + alloc((size_t)B * S * F);
  // decoder scratch aliases the (then-idle) qkvb region
  float* xd      = qkvb;
  float* q2      = xd + BN * D;
  float* ad      = q2 + BN * D;
  float* qkvd    = ad + BN * D;
  float* ffd     = qkvd + BN * 3 * D;
  float* logitsb = ffd + BN * F;
  int* toks = (int*)d_out;

  // ---------------- encoder ----------------
  embed_enc<<<B * S, 256, 0, stream>>>(ids, E, pos_e, xe);
  for (int l = 0; l < NL; ++l) {
    ln_kernel<<<B * S, 256, 0, stream>>>(xe, he);
    gemm128<0><<<dim3(3 * D / 128, B * S / 128), 256, 0, stream>>>(
        he, eai + (size_t)l * D * 3 * D, nullptr, qkvb, D, 3 * D);
    enc_attn<<<B * H * S, 256, 0, stream>>>(qkvb, maskp, ab);
    gemm128<1><<<dim3(D / 128, B * S / 128), 256, 0, stream>>>(
        ab, eao + (size_t)l * D * D, xe, xe, D, D);
    ln_kernel<<<B * S, 256, 0, stream>>>(xe, he);
    gemm128<2><<<dim3(F / 128, B * S / 128), 256, 0, stream>>>(
        he, ef1 + (size_t)l * D * F, nullptr, ffb, D, F);
    gemm128<1><<<dim3(D / 128, B * S / 128), 256, 0, stream>>>(
        ffb, ef2 + (size_t)l * F * D, xe, xe, F, D);
  }
  ln_kernel<<<B * S, 256, 0, stream>>>(xe, he);
  for (int l = 0; l < NL; ++l) {
    gemm128<0><<<dim3(2 * D / 128, B * S / 128), 256, 0, stream>>>(
        he, dckv + (size_t)l * D * 2 * D, nullptr,
        cKV + (size_t)l * B * S * 2 * D, D, 2 * D);
  }

  // ---------------- decoder: 80 sequential sampling steps ----------------
  for (int t = 0; t < T; ++t) {
    embed_dec<<<BN, 256, 0, stream>>>(E, pos_d, toks, xd, t);
    for (int l = 0; l < NL; ++l) {
      // self-attention block
      dec_gemm<0, true, true><<<3 * D / 16, 512, 0, stream>>>(
          xd, dsi + (size_t)l * D * 3 * D, nullptr, qkvd, cacheK, cacheV,
          D, 3 * D, t, l);
      dec_self_attn<<<BN * H, 128, 0, stream>>>(qkvd, cacheK, cacheV, ad, t, l);
      dec_gemm<1, false, false><<<D / 16, 512, 0, stream>>>(
          ad, dso + (size_t)l * D * D, xd, xd, nullptr, nullptr, D, D, 0, 0);
      // cross-attention block
      dec_gemm<0, true, false><<<D / 16, 512, 0, stream>>>(
          xd, dcq + (size_t)l * D * D, nullptr, q2, nullptr, nullptr, D, D, 0, 0);
      dec_cross_attn<<<BN * H, 256, 0, stream>>>(q2, cKV, maskp, ad, l);
      dec_gemm<1, false, false><<<D / 16, 512, 0, stream>>>(
          ad, dco + (size_t)l * D * D, xd, xd, nullptr, nullptr, D, D, 0, 0);
      // ffn block
      dec_gemm<2, true, false><<<F / 16, 512, 0, stream>>>(
          xd, df1 + (size_t)l * D * F, nullptr, ffd, nullptr, nullptr, D, F, 0, 0);
      dec_gemm<1, false, false><<<D / 16, 512, 0, stream>>>(
          ffd, df2 + (size_t)l * F * D, xd, xd, nullptr, nullptr, F, D, 0, 0);
    }
    logits_ln<<<(V + 255) / 256, 256, 0, stream>>>(xd, E, logitsb);
    topk_sample<<<BN, 256, 0, stream>>>(logitsb, toks, t);
  }
}

// Round 3
// 63650.378 us; speedup vs baseline: 1.3344x; 1.2316x over previous
//
#include <hip/hip_runtime.h>
#include <cstdint>
#include <cstddef>

#define DEV __device__ __forceinline__

// Problem constants
constexpr int V  = 96103;
constexpr int D  = 1024;
constexpr int H  = 16;
constexpr int DH = 64;
constexpr int F  = 4096;
constexpr int NL = 2;     // layers
constexpr int S  = 512;
constexpr int T  = 80;
constexpr int B  = 4;
constexpr int NS = 5;
constexpr int BN = 20;    // B*NS
constexpr int KTOP = 100;
constexpr int EOS = 1;

// ---------------------------------------------------------------- utilities

DEV float gelu_f(float x) {
  float x3 = x * x * x;
  float inner = 0.7978845608028654f * (x + 0.044715f * x3);
  float tt = tanhf(inner);
  return x * (0.5f * (1.0f + tt));
}

DEV void tf2x32(unsigned k0, unsigned k1, unsigned& x0, unsigned& x1) {
  unsigned ks2 = k0 ^ k1 ^ 0x1BD11BDAu;
#define TFR(rr) { x0 += x1; x1 = (x1 << rr) | (x1 >> (32 - rr)); x1 ^= x0; }
  x0 += k0; x1 += k1;
  TFR(13) TFR(15) TFR(26) TFR(6)
  x0 += k1;  x1 += ks2 + 1u;
  TFR(17) TFR(29) TFR(16) TFR(24)
  x0 += ks2; x1 += k0 + 2u;
  TFR(13) TFR(15) TFR(26) TFR(6)
  x0 += k0;  x1 += k1 + 3u;
  TFR(17) TFR(29) TFR(16) TFR(24)
  x0 += k1;  x1 += ks2 + 4u;
  TFR(13) TFR(15) TFR(26) TFR(6)
  x0 += ks2; x1 += k0 + 5u;
#undef TFR
}

DEV unsigned long long sort_key(float v, unsigned idx) {
  unsigned bb = __float_as_uint(v);
  bb = (bb & 0x80000000u) ? ~bb : (bb | 0x80000000u);
  return ((unsigned long long)bb << 32) | (unsigned long long)(0xFFFFFFFFu - idx);
}

// wave-parallel LN of BN x 1024 rows into LDS xs[20][1024]
template<int NWAVE>
DEV void ln_to_lds(const float* __restrict__ x, float* xs, int tid) {
  int w = tid >> 6, lane = tid & 63;
  for (int m = w; m < BN; m += NWAVE) {
    float4 v[4];
    float sum = 0.0f;
#pragma unroll
    for (int j = 0; j < 4; ++j) {
      v[j] = *(const float4*)(x + m * D + j * 256 + lane * 4);
      sum += v[j].x + v[j].y + v[j].z + v[j].w;
    }
#pragma unroll
    for (int o = 32; o > 0; o >>= 1) sum += __shfl_xor(sum, o);
    float mean = sum * (1.0f / 1024.0f);
    float vs = 0.0f;
#pragma unroll
    for (int j = 0; j < 4; ++j) {
      float a = v[j].x - mean, b = v[j].y - mean, c = v[j].z - mean, d = v[j].w - mean;
      vs += a * a + b * b + c * c + d * d;
    }
#pragma unroll
    for (int o = 32; o > 0; o >>= 1) vs += __shfl_xor(vs, o);
    float rsig = 1.0f / sqrtf(vs * (1.0f / 1024.0f) + 1e-5f);
#pragma unroll
    for (int j = 0; j < 4; ++j) {
      float4 ov;
      ov.x = (v[j].x - mean) * rsig; ov.y = (v[j].y - mean) * rsig;
      ov.z = (v[j].z - mean) * rsig; ov.w = (v[j].w - mean) * rsig;
      *(float4*)(xs + m * D + j * 256 + lane * 4) = ov;
    }
  }
}

// ---------------------------------------------------------------- embeddings

__global__ __launch_bounds__(256) void embed_enc(const int* __restrict__ ids,
                                                 const float* __restrict__ E,
                                                 const float* __restrict__ pos_e,
                                                 float* __restrict__ xe) {
  int row = blockIdx.x;
  int id = ids[row];
  const float* er = E + (size_t)id * D;
  const float* pr = pos_e + (size_t)(row % S) * D;
  float* xr = xe + (size_t)row * D;
  for (int j = threadIdx.x; j < D; j += 256)
    xr[j] = er[j] * 32.0f + pr[j];
}

__global__ __launch_bounds__(256) void embed_dec(const float* __restrict__ E,
                                                 const float* __restrict__ pos_d,
                                                 const int* __restrict__ toks,
                                                 float* __restrict__ xd, int t) {
  int bn = blockIdx.x;
  int prev = (t == 0) ? 0 : toks[bn * T + (t - 1)];
  const float* er = E + (size_t)prev * D;
  const float* pr = pos_d + (size_t)t * D;
  float* xr = xd + (size_t)bn * D;
  for (int j = threadIdx.x; j < D; j += 256)
    xr[j] = er[j] * 32.0f + pr[j];
}

// ---------------------------------------------------------------- layernorm (encoder)

__global__ __launch_bounds__(256) void ln_kernel(const float* __restrict__ x,
                                                 float* __restrict__ y) {
  __shared__ float red[256];
  __shared__ float sv[2];
  int tid = threadIdx.x;
  const float* xr = x + (size_t)blockIdx.x * D;
  float4 v = *(const float4*)(xr + tid * 4);
  red[tid] = v.x + v.y + v.z + v.w;
  __syncthreads();
  for (int k = 128; k > 0; k >>= 1) { if (tid < k) red[tid] += red[tid + k]; __syncthreads(); }
  if (tid == 0) sv[0] = red[0] * (1.0f / 1024.0f);
  __syncthreads();
  float m = sv[0];
  float dx = v.x - m, dy = v.y - m, dz = v.z - m, dw = v.w - m;
  red[tid] = dx * dx + dy * dy + dz * dz + dw * dw;
  __syncthreads();
  for (int k = 128; k > 0; k >>= 1) { if (tid < k) red[tid] += red[tid + k]; __syncthreads(); }
  if (tid == 0) sv[1] = 1.0f / sqrtf(red[0] * (1.0f / 1024.0f) + 1e-5f);
  __syncthreads();
  float r = sv[1];
  float* yr = y + (size_t)blockIdx.x * D;
  float4 o; o.x = dx * r; o.y = dy * r; o.z = dz * r; o.w = dw * r;
  *(float4*)(yr + tid * 4) = o;
}

// ---------------------------------------------------------------- encoder GEMM 128x128

template<int EPI>
__global__ __launch_bounds__(256) void gemm128(const float* __restrict__ A,
                                               const float* __restrict__ W,
                                               const float* X, float* C,
                                               int Kd, int Nd) {
  __shared__ __align__(16) float As[8][128];
  __shared__ __align__(16) float Bs[8][128];
  int tid = threadIdx.x;
  int n0 = blockIdx.x * 128, m0 = blockIdx.y * 128;
  int tx = tid & 15, ty = tid >> 4;
  int ar = tid >> 1, ac = (tid & 1) * 4;
  int br = tid >> 5, bc = (tid & 31) * 4;
  float acc[8][8] = {};
  for (int k0 = 0; k0 < Kd; k0 += 8) {
    float4 av = *(const float4*)(A + (size_t)(m0 + ar) * Kd + k0 + ac);
    float4 wv = *(const float4*)(W + (size_t)(k0 + br) * Nd + n0 + bc);
    __syncthreads();
    As[ac + 0][ar] = av.x; As[ac + 1][ar] = av.y;
    As[ac + 2][ar] = av.z; As[ac + 3][ar] = av.w;
    *(float4*)&Bs[br][bc] = wv;
    __syncthreads();
#pragma unroll
    for (int k = 0; k < 8; ++k) {
      float a8[8], b8[8];
      *(float4*)&a8[0] = *(const float4*)&As[k][ty * 8];
      *(float4*)&a8[4] = *(const float4*)&As[k][ty * 8 + 4];
      *(float4*)&b8[0] = *(const float4*)&Bs[k][tx * 8];
      *(float4*)&b8[4] = *(const float4*)&Bs[k][tx * 8 + 4];
#pragma unroll
      for (int i = 0; i < 8; ++i)
#pragma unroll
        for (int j = 0; j < 8; ++j)
          acc[i][j] = fmaf(a8[i], b8[j], acc[i][j]);
    }
  }
#pragma unroll
  for (int i = 0; i < 8; ++i) {
    int m = m0 + ty * 8 + i;
#pragma unroll
    for (int j = 0; j < 8; ++j) {
      int n = n0 + tx * 8 + j;
      float r = acc[i][j];
      size_t off = (size_t)m * Nd + n;
      if (EPI == 1) r = X[off] + r;
      if (EPI == 2) r = gelu_f(r);
      C[off] = r;
    }
  }
}

// ---------------------------------------------------------------- encoder attention

__global__ __launch_bounds__(256) void enc_attn(const float* __restrict__ qkv,
                                                const int* __restrict__ mask,
                                                float* __restrict__ ab) {
  __shared__ __align__(16) float qv[64];
  __shared__ float sc[512];
  __shared__ float red[256];
  __shared__ float sv[2];
  int tid = threadIdx.x;
  int q = blockIdx.x % S;
  int h = (blockIdx.x / S) % H;
  int b = blockIdx.x / (S * H);
  const float* qrow = qkv + (size_t)(b * S + q) * (3 * D) + h * 64;
  if (tid < 64) qv[tid] = qrow[tid];
  __syncthreads();
  float lmax = -INFINITY;
  for (int k = tid; k < S; k += 256) {
    const float* kr = qkv + (size_t)(b * S + k) * (3 * D) + D + h * 64;
    float dot = 0.0f;
#pragma unroll
    for (int d4 = 0; d4 < 16; ++d4) {
      float4 kk = *(const float4*)(kr + d4 * 4);
      float4 qq = *(const float4*)(qv + d4 * 4);
      dot += qq.x * kk.x + qq.y * kk.y + qq.z * kk.z + qq.w * kk.w;
    }
    float bias = (1.0f - (float)mask[b * S + k]) * -1e9f;
    float val = dot * 0.125f + bias;
    sc[k] = val;
    lmax = fmaxf(lmax, val);
  }
  red[tid] = lmax; __syncthreads();
  for (int k = 128; k > 0; k >>= 1) { if (tid < k) red[tid] = fmaxf(red[tid], red[tid + k]); __syncthreads(); }
  if (tid == 0) sv[0] = red[0];
  __syncthreads();
  float mx = sv[0];
  float lsum = 0.0f;
  for (int k = tid; k < S; k += 256) { float e = expf(sc[k] - mx); sc[k] = e; lsum += e; }
  red[tid] = lsum; __syncthreads();
  for (int k = 128; k > 0; k >>= 1) { if (tid < k) red[tid] += red[tid + k]; __syncthreads(); }
  if (tid == 0) sv[1] = red[0];
  __syncthreads();
  float den = sv[1];
  for (int k = tid; k < S; k += 256) sc[k] = sc[k] / den;
  __syncthreads();
  int d = tid & 63, c = tid >> 6;
  const float* vb = qkv + (size_t)(b * S) * (3 * D) + 2 * D + h * 64 + d;
  float part = 0.0f;
  for (int k = c * 128; k < c * 128 + 128; ++k)
    part = fmaf(sc[k], vb[(size_t)k * (3 * D)], part);
  red[tid] = part; __syncthreads();
  if (tid < 64) {
    float o = red[tid] + red[tid + 64] + red[tid + 128] + red[tid + 192];
    ab[(size_t)(b * S + q) * D + h * 64 + tid] = o;
  }
}

// ---------------------------------------------------------------- fused decode GEMM
// out[20,Nd] = epi( LN?(x)[20,Kd] @ W[Kd,Nd] )
// LN applied algebraically: sum((a*x+b)*w) = a*sum(x*w) + b*sum(w).
// 512 threads: c = tid%CT (col), ks = tid/CT (K-split group).
// EPI: 0 none, 1 residual add, 2 gelu.  KV: qkv epilogue routing to caches.

template<int CT, int EPI, bool KV, bool LNIN>
__global__ __launch_bounds__(512) void dec_gemm(const float* __restrict__ x,
                                                const float* __restrict__ W,
                                                const float* Xres, float* Cout,
                                                float* __restrict__ cacheK,
                                                float* __restrict__ cacheV,
                                                int Kd, int Nd, int t, int l) {
  constexpr int KSP = 512 / CT;
  __shared__ float red[CT * 20 * (KSP + 1)];
  __shared__ float redw[CT * (KSP + 1)];
  __shared__ float sab[40];   // a[m]=rstd, b[m]=-mean*rstd
  int tid = threadIdx.x;
  if constexpr (LNIN) {
    // per-row LN stats (Kd must be 1024): wave w handles rows w, w+8, ...
    int w = tid >> 6, lane = tid & 63;
    for (int m = w; m < BN; m += 8) {
      const float* xr = x + (size_t)m * 1024 + lane * 16;
      float4 v[4];
      float sum = 0.0f;
#pragma unroll
      for (int j = 0; j < 4; ++j) {
        v[j] = *(const float4*)(xr + j * 4);
        sum += v[j].x + v[j].y + v[j].z + v[j].w;
      }
#pragma unroll
      for (int o = 32; o > 0; o >>= 1) sum += __shfl_xor(sum, o);
      float mean = sum * (1.0f / 1024.0f);
      float vs = 0.0f;
#pragma unroll
      for (int j = 0; j < 4; ++j) {
        float a = v[j].x - mean, b = v[j].y - mean, c2 = v[j].z - mean, d = v[j].w - mean;
        vs += a * a + b * b + c2 * c2 + d * d;
      }
#pragma unroll
      for (int o = 32; o > 0; o >>= 1) vs += __shfl_xor(vs, o);
      float rstd = 1.0f / sqrtf(vs * (1.0f / 1024.0f) + 1e-5f);
      if (lane == 0) { sab[m] = rstd; sab[20 + m] = -mean * rstd; }
    }
    __syncthreads();
  }
  int c = tid % CT, ks = tid / CT;
  int klen = Kd / KSP;
  const float* Wp = W + (size_t)(ks * klen) * Nd + blockIdx.x * CT + c;
  float acc[20] = {};
  float accw = 0.0f;
  for (int kk = 0; kk < klen; kk += 8) {
    float wv[8];
#pragma unroll
    for (int u = 0; u < 8; ++u) wv[u] = Wp[(size_t)u * Nd];
    Wp += (size_t)8 * Nd;
    if constexpr (LNIN) {
      accw += wv[0] + wv[1] + wv[2] + wv[3] + wv[4] + wv[5] + wv[6] + wv[7];
    }
    int kb = ks * klen + kk;
#pragma unroll
    for (int m = 0; m < 20; ++m) {
      float4 x0 = *(const float4*)(x + (size_t)m * Kd + kb);
      float4 x1 = *(const float4*)(x + (size_t)m * Kd + kb + 4);
      float a = acc[m];
      a = fmaf(x0.x, wv[0], a); a = fmaf(x0.y, wv[1], a);
      a = fmaf(x0.z, wv[2], a); a = fmaf(x0.w, wv[3], a);
      a = fmaf(x1.x, wv[4], a); a = fmaf(x1.y, wv[5], a);
      a = fmaf(x1.z, wv[6], a); a = fmaf(x1.w, wv[7], a);
      acc[m] = a;
    }
  }
#pragma unroll
  for (int m = 0; m < 20; ++m) red[(c * 20 + m) * (KSP + 1) + ks] = acc[m];
  if constexpr (LNIN) redw[c * (KSP + 1) + ks] = accw;
  __syncthreads();
  if (tid < CT * 20) {
    int cc = tid % CT, m = tid / CT;
    const float* rp = red + (cc * 20 + m) * (KSP + 1);
    float s = 0.0f;
#pragma unroll
    for (int k2 = 0; k2 < KSP; ++k2) s += rp[k2];
    if constexpr (LNIN) {
      const float* rw = redw + cc * (KSP + 1);
      float sw = 0.0f;
#pragma unroll
      for (int k2 = 0; k2 < KSP; ++k2) sw += rw[k2];
      s = sab[m] * s + sab[20 + m] * sw;
    }
    int ng = blockIdx.x * CT + cc;
    if constexpr (KV) {
      if (ng < D) {
        Cout[(size_t)m * Nd + ng] = s;
      } else if (ng < 2 * D) {
        cacheK[(((size_t)l * BN + m) * T + t) * D + (ng - D)] = s;
      } else {
        cacheV[(((size_t)l * BN + m) * T + t) * D + (ng - 2 * D)] = s;
      }
    } else {
      size_t off = (size_t)m * Nd + ng;
      if (EPI == 1) s = Xres[off] + s;
      if (EPI == 2) s = gelu_f(s);
      Cout[off] = s;
    }
  }
}

// ---------------------------------------------------------------- decoder self-attn

__global__ __launch_bounds__(128) void dec_self_attn(const float* __restrict__ qkvd,
                                                     const float* __restrict__ cacheK,
                                                     const float* __restrict__ cacheV,
                                                     float* __restrict__ ad, int t, int l) {
  __shared__ __align__(16) float qv[64];
  __shared__ float sc[96];
  __shared__ float sv[2];
  int tid = threadIdx.x;
  int bn = blockIdx.x >> 4;
  int h = blockIdx.x & 15;
  int n = t + 1;
  if (tid < 64) qv[tid] = qkvd[(size_t)bn * (3 * D) + h * 64 + tid];
  __syncthreads();
  if (tid < n) {
    const float* kr = cacheK + (((size_t)l * BN + bn) * T + tid) * D + h * 64;
    float dot = 0.0f;
#pragma unroll
    for (int d4 = 0; d4 < 16; ++d4) {
      float4 kk = *(const float4*)(kr + d4 * 4);
      float4 qq = *(const float4*)(qv + d4 * 4);
      dot += qq.x * kk.x + qq.y * kk.y + qq.z * kk.z + qq.w * kk.w;
    }
    sc[tid] = dot * 0.125f;
  }
  __syncthreads();
  if (tid == 0) {
    float mx = -INFINITY;
    for (int k = 0; k < n; ++k) mx = fmaxf(mx, sc[k]);
    sv[0] = mx;
  }
  __syncthreads();
  if (tid < n) sc[tid] = expf(sc[tid] - sv[0]);
  __syncthreads();
  if (tid == 0) {
    float s = 0.0f;
    for (int k = 0; k < n; ++k) s += sc[k];
    sv[1] = s;
  }
  __syncthreads();
  if (tid < n) sc[tid] = sc[tid] / sv[1];
  __syncthreads();
  if (tid < 64) {
    const float* vb = cacheV + ((size_t)l * BN + bn) * T * D + h * 64 + tid;
    float o = 0.0f;
    for (int k = 0; k < n; ++k) o = fmaf(sc[k], vb[(size_t)k * D], o);
    ad[(size_t)bn * D + h * 64 + tid] = o;
  }
}

// ---------------------------------------------------------------- decoder cross-attn

__global__ __launch_bounds__(256) void dec_cross_attn(const float* __restrict__ q2,
                                                      const float* __restrict__ cKV,
                                                      const int* __restrict__ mask,
                                                      float* __restrict__ ad, int l) {
  __shared__ __align__(16) float qv[64];
  __shared__ float sc[512];
  __shared__ float red[256];
  __shared__ float sv[2];
  int tid = threadIdx.x;
  int bn = blockIdx.x >> 4;
  int h = blockIdx.x & 15;
  int b = bn / NS;
  const float* base = cKV + ((size_t)l * B + b) * S * (2 * D);
  if (tid < 64) qv[tid] = q2[(size_t)bn * D + h * 64 + tid];
  __syncthreads();
  float lmax = -INFINITY;
  for (int s = tid; s < S; s += 256) {
    const float* kr = base + (size_t)s * (2 * D) + h * 64;
    float dot = 0.0f;
#pragma unroll
    for (int d4 = 0; d4 < 16; ++d4) {
      float4 kk = *(const float4*)(kr + d4 * 4);
      float4 qq = *(const float4*)(qv + d4 * 4);
      dot += qq.x * kk.x + qq.y * kk.y + qq.z * kk.z + qq.w * kk.w;
    }
    float bias = (1.0f - (float)mask[b * S + s]) * -1e9f;
    float val = dot * 0.125f + bias;
    sc[s] = val;
    lmax = fmaxf(lmax, val);
  }
  red[tid] = lmax; __syncthreads();
  for (int k = 128; k > 0; k >>= 1) { if (tid < k) red[tid] = fmaxf(red[tid], red[tid + k]); __syncthreads(); }
  if (tid == 0) sv[0] = red[0];
  __syncthreads();
  float mx = sv[0];
  float lsum = 0.0f;
  for (int s = tid; s < S; s += 256) { float e = expf(sc[s] - mx); sc[s] = e; lsum += e; }
  red[tid] = lsum; __syncthreads();
  for (int k = 128; k > 0; k >>= 1) { if (tid < k) red[tid] += red[tid + k]; __syncthreads(); }
  if (tid == 0) sv[1] = red[0];
  __syncthreads();
  float den = sv[1];
  for (int s = tid; s < S; s += 256) sc[s] = sc[s] / den;
  __syncthreads();
  int d = tid & 63, c = tid >> 6;
  const float* vb = base + D + h * 64 + d;
  float part = 0.0f;
  for (int s = c * 128; s < c * 128 + 128; ++s)
    part = fmaf(sc[s], vb[(size_t)s * (2 * D)], part);
  red[tid] = part; __syncthreads();
  if (tid < 64) {
    float o = red[tid] + red[tid + 64] + red[tid + 128] + red[tid + 192];
    ad[(size_t)bn * D + h * 64 + tid] = o;
  }
}

// ---------------------------------------------------------------- logits = LN(x) @ E^T
// 256 thr = 4 waves: wave = (mhalf, nset); each lane handles 3 vocab rows.
// block covers 384 vocab rows; grid = ceil(V/384).

__global__ __launch_bounds__(256) void logits_ln(const float* __restrict__ xd,
                                                 const float* __restrict__ E,
                                                 float* __restrict__ logits) {
  __shared__ float xs[20 * 1024];
  int tid = threadIdx.x;
  ln_to_lds<4>(xd, xs, tid);
  __syncthreads();
  int w = tid >> 6, l = tid & 63;
  int mh = (w >> 1) * 10;
  int ns = w & 1;
  int nb = blockIdx.x * 384 + ns * 192 + l;
  int n1 = nb + 64, n2 = nb + 128;
  const float* e0 = E + (size_t)(nb < V ? nb : V - 1) * D;
  const float* e1 = E + (size_t)(n1 < V ? n1 : V - 1) * D;
  const float* e2 = E + (size_t)(n2 < V ? n2 : V - 1) * D;
  const float* xb = xs + mh * 1024;
  float acc[10][3] = {};
  for (int k = 0; k < 1024; k += 4) {
    float4 ea = *(const float4*)(e0 + k);
    float4 eb = *(const float4*)(e1 + k);
    float4 ec = *(const float4*)(e2 + k);
#pragma unroll
    for (int m = 0; m < 10; ++m) {
      const float4 xv = *(const float4*)(xb + m * 1024 + k);
      float a0 = acc[m][0], a1 = acc[m][1], a2 = acc[m][2];
      a0 = fmaf(xv.x, ea.x, a0); a0 = fmaf(xv.y, ea.y, a0);
      a0 = fmaf(xv.z, ea.z, a0); a0 = fmaf(xv.w, ea.w, a0);
      a1 = fmaf(xv.x, eb.x, a1); a1 = fmaf(xv.y, eb.y, a1);
      a1 = fmaf(xv.z, eb.z, a1); a1 = fmaf(xv.w, eb.w, a1);
      a2 = fmaf(xv.x, ec.x, a2); a2 = fmaf(xv.y, ec.y, a2);
      a2 = fmaf(xv.z, ec.z, a2); a2 = fmaf(xv.w, ec.w, a2);
      acc[m][0] = a0; acc[m][1] = a1; acc[m][2] = a2;
    }
  }
#pragma unroll
  for (int m = 0; m < 10; ++m) {
    if (nb < V) logits[(size_t)(mh + m) * V + nb] = acc[m][0];
    if (n1 < V) logits[(size_t)(mh + m) * V + n1] = acc[m][1];
    if (n2 < V) logits[(size_t)(mh + m) * V + n2] = acc[m][2];
  }
}

// ---------------------------------------------------------------- top-k + gumbel sample

__global__ __launch_bounds__(256) void topk_sample(const float* __restrict__ logits,
                                                   int* __restrict__ toks, int t) {
  __shared__ unsigned long long keys[2048];
  __shared__ float svals[128];
  __shared__ unsigned sidx[128];
  int tid = threadIdx.x;
  int bn = blockIdx.x;
  const float* row = logits + (size_t)bn * V;

  float tv[8]; unsigned ti[8];
#pragma unroll
  for (int j = 0; j < 8; ++j) { tv[j] = -INFINITY; ti[j] = 0xFFFFFFFFu; }

  for (int i = tid; i < V; i += 256) {
    float v = row[i];
    if (t < 6 && i == EOS) v = -1e9f;
    if (v > tv[7]) {
      tv[7] = v; ti[7] = (unsigned)i;
#pragma unroll
      for (int j = 7; j > 0; --j) {
        if (tv[j] > tv[j - 1]) {
          float a = tv[j]; tv[j] = tv[j - 1]; tv[j - 1] = a;
          unsigned bi = ti[j]; ti[j] = ti[j - 1]; ti[j - 1] = bi;
        }
      }
    }
  }
#pragma unroll
  for (int j = 0; j < 8; ++j) keys[tid * 8 + j] = ~sort_key(tv[j], ti[j]);
  __syncthreads();

  for (int ksz = 2; ksz <= 2048; ksz <<= 1) {
    for (int jj = ksz >> 1; jj > 0; jj >>= 1) {
      for (int i = tid; i < 2048; i += 256) {
        int ixj = i ^ jj;
        if (ixj > i) {
          unsigned long long a = keys[i], b2 = keys[ixj];
          bool up = ((i & ksz) == 0);
          if ((a > b2) == up) { keys[i] = b2; keys[ixj] = a; }
        }
      }
      __syncthreads();
    }
  }

  if (tid < KTOP) {
    unsigned long long kk = ~keys[tid];
    unsigned sb = (unsigned)(kk >> 32);
    unsigned idx = 0xFFFFFFFFu - (unsigned)(kk & 0xFFFFFFFFull);
    unsigned fb = (sb & 0x80000000u) ? (sb ^ 0x80000000u) : ~sb;
    float v = __uint_as_float(fb);
    unsigned a0 = 0u, a1 = (unsigned)t;
    tf2x32(0u, 1234u, a0, a1);
    unsigned c0 = 0u, c1 = (unsigned)(bn * KTOP + tid);
    tf2x32(a0, a1, c0, c1);
    unsigned bits = c0 ^ c1;
    float f = __uint_as_float((bits >> 9) | 0x3f800000u) - 1.0f;
    float u = fmaxf(f, 1.17549435e-38f);
    float g = -logf(-logf(u));
    svals[tid] = v + g;
    sidx[tid] = idx;
  }
  __syncthreads();
  if (tid == 0) {
    int best = 0; float bv = svals[0];
    for (int j = 1; j < KTOP; ++j) { if (svals[j] > bv) { bv = svals[j]; best = j; } }
    toks[bn * T + t] = (int)sidx[best];
  }
}

// ---------------------------------------------------------------- host driver

extern "C" void kernel_launch(void* const* d_in, const int* in_sizes, int n_in,
                              void* d_out, int out_size, void* d_ws, size_t ws_size,
                              hipStream_t stream) {
  (void)in_sizes; (void)n_in; (void)out_size; (void)ws_size;

  const int*   ids   = (const int*)d_in[0];
  const int*   maskp = (const int*)d_in[1];
  const float* E     = (const float*)d_in[2];
  const float* pos_e = (const float*)d_in[3];
  const float* pos_d = (const float*)d_in[4];
  const float* eai   = (const float*)d_in[5];
  const float* eao   = (const float*)d_in[6];
  const float* ef1   = (const float*)d_in[7];
  const float* ef2   = (const float*)d_in[8];
  const float* dsi   = (const float*)d_in[9];
  const float* dso   = (const float*)d_in[10];
  const float* dcq   = (const float*)d_in[11];
  const float* dckv  = (const float*)d_in[12];
  const float* dco   = (const float*)d_in[13];
  const float* df1   = (const float*)d_in[14];
  const float* df2   = (const float*)d_in[15];

  float* ws = (float*)d_ws;
  size_t o = 0;
  auto alloc = [&](size_t n) { size_t r = o; o += (n + 63) & ~(size_t)63; return r; };
  float* cKV    = ws + alloc((size_t)NL * B * S * 2 * D);
  float* cacheK = ws + alloc((size_t)NL * BN * T * D);
  float* cacheV = ws + alloc((size_t)NL * BN * T * D);
  float* xe     = ws + alloc((size_t)B * S * D);
  float* he     = ws + alloc((size_t)B * S * D);
  float* qkvb   = ws + alloc((size_t)B * S * 3 * D);
  float* ab     = ws + alloc((size_t)B * S * D);
  float* ffb    = ws + alloc((size_t)B * S * F);
  // decoder scratch aliases the (then-idle) qkvb region
  float* xd      = qkvb;
  float* q2      = xd + BN * D;
  float* ad      = q2 + BN * D;
  float* qkvd    = ad + BN * D;
  float* ffd     = qkvd + BN * 3 * D;
  float* logitsb = ffd + BN * F;
  int* toks = (int*)d_out;

  // ---------------- encoder ----------------
  embed_enc<<<B * S, 256, 0, stream>>>(ids, E, pos_e, xe);
  for (int l = 0; l < NL; ++l) {
    ln_kernel<<<B * S, 256, 0, stream>>>(xe, he);
    gemm128<0><<<dim3(3 * D / 128, B * S / 128), 256, 0, stream>>>(
        he, eai + (size_t)l * D * 3 * D, nullptr, qkvb, D, 3 * D);
    enc_attn<<<B * H * S, 256, 0, stream>>>(qkvb, maskp, ab);
    gemm128<1><<<dim3(D / 128, B * S / 128), 256, 0, stream>>>(
        ab, eao + (size_t)l * D * D, xe, xe, D, D);
    ln_kernel<<<B * S, 256, 0, stream>>>(xe, he);
    gemm128<2><<<dim3(F / 128, B * S / 128), 256, 0, stream>>>(
        he, ef1 + (size_t)l * D * F, nullptr, ffb, D, F);
    gemm128<1><<<dim3(D / 128, B * S / 128), 256, 0, stream>>>(
        ffb, ef2 + (size_t)l * F * D, xe, xe, F, D);
  }
  ln_kernel<<<B * S, 256, 0, stream>>>(xe, he);
  for (int l = 0; l < NL; ++l) {
    gemm128<0><<<dim3(2 * D / 128, B * S / 128), 256, 0, stream>>>(
        he, dckv + (size_t)l * D * 2 * D, nullptr,
        cKV + (size_t)l * B * S * 2 * D, D, 2 * D);
  }

  // ---------------- decoder: 80 sequential sampling steps ----------------
  for (int t = 0; t < T; ++t) {
    embed_dec<<<BN, 256, 0, stream>>>(E, pos_d, toks, xd, t);
    for (int l = 0; l < NL; ++l) {
      // self-attention block
      dec_gemm<16, 0, true, true><<<3 * D / 16, 512, 0, stream>>>(
          xd, dsi + (size_t)l * D * 3 * D, nullptr, qkvd, cacheK, cacheV,
          D, 3 * D, t, l);
      dec_self_attn<<<BN * H, 128, 0, stream>>>(qkvd, cacheK, cacheV, ad, t, l);
      dec_gemm<8, 1, false, false><<<D / 8, 512, 0, stream>>>(
          ad, dso + (size_t)l * D * D, xd, xd, nullptr, nullptr, D, D, 0, 0);
      // cross-attention block
      dec_gemm<8, 0, false, true><<<D / 8, 512, 0, stream>>>(
          xd, dcq + (size_t)l * D * D, nullptr, q2, nullptr, nullptr, D, D, 0, 0);
      dec_cross_attn<<<BN * H, 256, 0, stream>>>(q2, cKV, maskp, ad, l);
      dec_gemm<8, 1, false, false><<<D / 8, 512, 0, stream>>>(
          ad, dco + (size_t)l * D * D, xd, xd, nullptr, nullptr, D, D, 0, 0);
      // ffn block
      dec_gemm<16, 2, false, true><<<F / 16, 512, 0, stream>>>(
          xd, df1 + (size_t)l * D * F, nullptr, ffd, nullptr, nullptr, D, F, 0, 0);
      dec_gemm<8, 1, false, false><<<D / 8, 512, 0, stream>>>(
          ffd, df2 + (size_t)l * F * D, xd, xd, nullptr, nullptr, F, D, 0, 0);
    }
    logits_ln<<<(V + 383) / 384, 256, 0, stream>>>(xd, E, logitsb);
    topk_sample<<<BN, 256, 0, stream>>>(logitsb, toks, t);
  }
}